// Round 2
// baseline (201.222 us; speedup 1.0000x reference)
//
#include <hip/hip_runtime.h>

// AdaptedGaussianConditional: v = inputs - means; nearest-codebook symbol via
// exact lower_bound semantics (tie -> lower index); dequant = codebook[sym] + means.
// Outputs concatenated: [dequant fp32 N | symbols-as-f32 N].
//
// R2: latency-bound fix. (a) batch 4 float4-quads per thread with all 8 global
// loads hoisted (4x MLP per wave); (b) LUT entry packed into ONE float4
// {left,right,symf,code} -> single ds_read_b128, chain depth 1; (c) exact
// bucketization with NO guard band: bucket map is monotone, so a bucket with no
// codebook point mapped into it (bit-identical map shared by build+main) has a
// constant clipped lower_bound. Dirty buckets (~25% of elems at NB=1024) store
// {start,count} and do an exact <=count corrective scan. LDS 17.3KB -> 9 blk/CU.

#define LVL 256
#define NB  1024
#define QPT 4           // float4 quads per thread, loads hoisted

// Shared by build & main kernels — MUST be bit-identical in both.
__device__ __forceinline__ int bucket_of(float v, float lo, float scale) {
    int b = (int)floorf((v - lo) * scale);
    return min(max(b, 0), NB - 1);
}

// ---------------- build kernel: 1 block, 256 threads -> NB float4 LUT in ws ----
// entry.w bits >= 0 : uniform bucket -> {left, right, symf, 0}
// entry.w bits <  0 : dirty  -> w = 0x80000000 | (A << 10) | cnt
//   A = #{j : bucket(uv[j]) < b} (valid lower_bound start), cnt = #{j in bucket b}
__global__ __launch_bounds__(256) void agc_build_lut(
    const float* __restrict__ uv, float4* __restrict__ lut)
{
    __shared__ float s_uv[LVL];
    __shared__ int   s_b[LVL];
    int t = threadIdx.x;
    s_uv[t] = uv[t];
    __syncthreads();
    const float lo    = s_uv[0];
    const float scale = (float)NB / (s_uv[LVL - 1] - lo);
    s_b[t] = bucket_of(s_uv[t], lo, scale);
    __syncthreads();

    #pragma unroll
    for (int q = 0; q < NB / 256; ++q) {
        int b = q * 256 + t;
        int A = 0, cnt = 0;
        for (int j = 0; j < LVL; ++j) {
            int bj = s_b[j];
            A   += (bj <  b);
            cnt += (bj == b);
        }
        float4 e;
        if (cnt == 0) {
            int idx = min(max(A, 1), LVL - 1);
            e.x = s_uv[idx - 1];
            e.y = s_uv[idx];
            e.z = (float)(idx - 1);
            e.w = 0.0f;                                   // uniform marker
        } else {
            unsigned w = 0x80000000u | ((unsigned)A << 10) | (unsigned)cnt;
            e.x = 0.0f; e.y = 0.0f; e.z = 0.0f;
            e.w = __int_as_float((int)w);
        }
        lut[b] = e;
    }
}

// ---------------- main kernel ----------------
__global__ __launch_bounds__(256) void agc_quant_lut(
    const float* __restrict__ inputs,
    const float* __restrict__ means,
    const float* __restrict__ uv,
    const float4* __restrict__ lut,
    float* __restrict__ out_deq,
    float* __restrict__ out_sym,
    int n4, int n, int gstride)
{
    __shared__ float  s_uv[LVL];
    __shared__ float4 s_lut[NB];

    int t = threadIdx.x;
    s_uv[t] = uv[t];
    #pragma unroll
    for (int q = 0; q < NB / 256; ++q)
        s_lut[q * 256 + t] = lut[q * 256 + t];
    __syncthreads();

    const float lo    = s_uv[0];
    const float scale = (float)NB / (s_uv[LVL - 1] - lo);

    const int base = blockIdx.x * blockDim.x + t;

    // ---- load phase: all global loads issued up front (8 in flight) ----
    float4 in[QPT], mn[QPT];
    bool   ok[QPT];
    #pragma unroll
    for (int k = 0; k < QPT; ++k) {
        int i = base + k * gstride;
        ok[k] = (i < n4);
        if (ok[k]) {
            in[k] = reinterpret_cast<const float4*>(inputs)[i];
            mn[k] = reinterpret_cast<const float4*>(means)[i];
        }
    }

    // ---- compute + store per quad ----
    #pragma unroll
    for (int k = 0; k < QPT; ++k) {
        if (!ok[k]) continue;
        int i = base + k * gstride;

        float vs[4] = {in[k].x - mn[k].x, in[k].y - mn[k].y,
                       in[k].z - mn[k].z, in[k].w - mn[k].w};
        float ms[4] = {mn[k].x, mn[k].y, mn[k].z, mn[k].w};
        float dq[4], sy[4];

        #pragma unroll
        for (int e4 = 0; e4 < 4; ++e4) {
            float v = vs[e4];
            int b = bucket_of(v, lo, scale);

            float4 e = s_lut[b];                 // ds_read_b128, chain depth 1
            int w = __float_as_int(e.w);
            float left = e.x, right = e.y, basef = e.z;

            if (w < 0) {                         // dirty bucket: exact scan
                int A   = (w >> 10) & 0x3FF;
                int cnt =  w        & 0x3FF;
                int s = A, end = A + cnt;
                while (s < end && s_uv[s] < v) ++s;
                int idx = min(max(s, 1), LVL - 1);
                left  = s_uv[idx - 1];
                right = s_uv[idx];
                basef = (float)(idx - 1);
            }

            bool tl = (fabsf(v - left) <= fabsf(v - right));  // identical to reference
            sy[e4] = tl ? basef : basef + 1.0f;
            dq[e4] = (tl ? left : right) + ms[e4];
        }

        reinterpret_cast<float4*>(out_deq)[i] = make_float4(dq[0], dq[1], dq[2], dq[3]);
        reinterpret_cast<float4*>(out_sym)[i] = make_float4(sy[0], sy[1], sy[2], sy[3]);
    }

    // tail (n % 4 != 0) — n here is 12.58M, rem = 0
    if (blockIdx.x == 0 && t == 0) {
        for (int j = n4 * 4; j < n; ++j) {
            float m = means[j];
            float v = inputs[j] - m;
            int l = 0, h = LVL;
            for (int s = 0; s < 8; ++s) {
                int mm = (l + h) >> 1;
                bool r = (s_uv[mm] < v);
                l = r ? (mm + 1) : l;
                h = r ? h : mm;
            }
            int idx = min(max(l, 1), LVL - 1);
            float left = s_uv[idx - 1], right = s_uv[idx];
            bool tl = fabsf(v - left) <= fabsf(v - right);
            out_deq[j] = (tl ? left : right) + m;
            out_sym[j] = (float)(tl ? idx - 1 : idx);
        }
    }
}

// ---------------- safety fallback (no/short workspace): binary-search kernel ----
__global__ __launch_bounds__(256) void agc_quant_fallback(
    const float* __restrict__ inputs,
    const float* __restrict__ means,
    const float* __restrict__ uv,
    float* __restrict__ out_deq,
    float* __restrict__ out_sym,
    int n4, int n)
{
    __shared__ float s_uv[LVL];
    s_uv[threadIdx.x] = uv[threadIdx.x];
    __syncthreads();

    int i = blockIdx.x * blockDim.x + threadIdx.x;
    if (i < n4) {
        float4 in = reinterpret_cast<const float4*>(inputs)[i];
        float4 mn = reinterpret_cast<const float4*>(means)[i];
        float vs[4] = {in.x - mn.x, in.y - mn.y, in.z - mn.z, in.w - mn.w};
        float ms[4] = {mn.x, mn.y, mn.z, mn.w};
        float dq[4], sy[4];
        #pragma unroll
        for (int k = 0; k < 4; ++k) {
            float v = vs[k];
            int lo = 0, hi = LVL;
            #pragma unroll
            for (int s = 0; s < 8; ++s) {
                int mid = (lo + hi) >> 1;
                bool r = (s_uv[mid] < v);
                lo = r ? (mid + 1) : lo;
                hi = r ? hi : mid;
            }
            int idx = min(max(lo, 1), LVL - 1);
            float left = s_uv[idx - 1], right = s_uv[idx];
            bool tl = (fabsf(v - left) <= fabsf(v - right));
            sy[k] = (float)(tl ? idx - 1 : idx);
            dq[k] = (tl ? left : right) + ms[k];
        }
        reinterpret_cast<float4*>(out_deq)[i] = make_float4(dq[0], dq[1], dq[2], dq[3]);
        reinterpret_cast<float4*>(out_sym)[i] = make_float4(sy[0], sy[1], sy[2], sy[3]);
    }
    if (blockIdx.x == 0 && threadIdx.x == 0) {
        for (int j = n4 * 4; j < n; ++j) {
            float m = means[j];
            float v = inputs[j] - m;
            int lo = 0, hi = LVL;
            for (int s = 0; s < 8; ++s) {
                int mid = (lo + hi) >> 1;
                bool r = (s_uv[mid] < v);
                lo = r ? (mid + 1) : lo;
                hi = r ? hi : mid;
            }
            int idx = min(max(lo, 1), LVL - 1);
            float left = s_uv[idx - 1], right = s_uv[idx];
            bool tl = fabsf(v - left) <= fabsf(v - right);
            out_deq[j] = (tl ? left : right) + m;
            out_sym[j] = (float)(tl ? idx - 1 : idx);
        }
    }
}

extern "C" void kernel_launch(void* const* d_in, const int* in_sizes, int n_in,
                              void* d_out, int out_size, void* d_ws, size_t ws_size,
                              hipStream_t stream)
{
    const float* inputs = (const float*)d_in[0];
    const float* means  = (const float*)d_in[1];
    const float* uv     = (const float*)d_in[2];

    int n  = in_sizes[0];        // 12,582,912
    int n4 = n / 4;

    float* out     = (float*)d_out;
    float* out_deq = out;        // first N: dequant
    float* out_sym = out + n;    // second N: symbols (exact float values)

    size_t need = (size_t)NB * sizeof(float4);      // 16 KB
    if (d_ws != nullptr && ws_size >= need) {
        agc_build_lut<<<1, 256, 0, stream>>>(uv, (float4*)d_ws);

        // each thread handles QPT float4 quads; grid covers n4 exactly
        long long per_blk = 256LL * QPT;
        int blocks = (int)((n4 + per_blk - 1) / per_blk);   // 3072 for this shape
        if (blocks < 1) blocks = 1;
        int gstride = blocks * 256;
        agc_quant_lut<<<blocks, 256, 0, stream>>>(
            inputs, means, uv, (const float4*)d_ws,
            out_deq, out_sym, n4, n, gstride);
    } else {
        int blocks = (n4 + 255) / 256;
        if (blocks < 1) blocks = 1;
        agc_quant_fallback<<<blocks, 256, 0, stream>>>(
            inputs, means, uv, out_deq, out_sym, n4, n);
    }
}

// Round 4
// 188.266 us; speedup vs baseline: 1.0688x; 1.0688x over previous
//
#include <hip/hip_runtime.h>

// AdaptedGaussianConditional: v = inputs - means; nearest-codebook symbol via
// exact lower_bound semantics (tie -> lower index); dequant = codebook[sym] + means.
// Outputs concatenated: [dequant fp32 N | symbols-as-f32 N].
//
// R4 == R3 resubmitted (infra failure, kernel never benched).
// R3: fully branchless bucket LUT. Each bucket stores 2 split points + 4
// consecutive codebook values: sel=(p0<v)+(p1<v); left=c[sel]; right=c[sel+1];
// base=A-1+sel. Covers cnt<=2 codebook points per bucket (99.8% of mass at
// NB=1024). >=3-point / edge buckets: masked exact scan (rare). No divergent
// hot path, 2 independent ds_read_b128 per element, chain depth 1.
// Build kernel parallelized (4 blocks). Flat grid, loads hoisted (QPT=4).

#define LVL 256
#define NB  1024
#define QPT 4

// Shared by build & main kernels — MUST be bit-identical in both.
// Weakly monotone in v  =>  bucket(uv[j]) < bucket(v) implies uv[j] < v,
// and bucket(uv[j]) > bucket(v) implies uv[j] > v (exactness of fallback scan).
__device__ __forceinline__ int bucket_of(float v, float lo, float scale) {
    int b = (int)floorf((v - lo) * scale);
    return min(max(b, 0), NB - 1);
}

// ---------------- build kernel: NB/256 blocks ----------------
// lutA[b] = {p0, p1, c0, c1}   lutB[b] = {c2, c3, unused, basepack}
// basepack int >= 0 : branchless entry, base = basepack + sel
// basepack int <  0 : fallback, exact scan start = -basepack - 1
__global__ __launch_bounds__(256) void agc_build_lut(
    const float* __restrict__ uv, float4* __restrict__ lutA, float4* __restrict__ lutB)
{
    __shared__ float s_uv[LVL];
    __shared__ int   s_b[LVL];
    int t = threadIdx.x;
    s_uv[t] = uv[t];
    __syncthreads();
    const float lo    = s_uv[0];
    const float scale = (float)NB / (s_uv[LVL - 1] - lo);
    s_b[t] = bucket_of(s_uv[t], lo, scale);
    __syncthreads();

    int b = blockIdx.x * 256 + t;
    if (b >= NB) return;

    int A = 0, cnt = 0;
    for (int j = 0; j < LVL; ++j) {      // broadcast reads, cheap
        int bj = s_b[j];
        A   += (bj <  b);
        cnt += (bj == b);
    }

    const float INF = __builtin_inff();
    float4 ea, eb;
    if (cnt == 0) {
        // constant clipped lower_bound over the whole bucket
        int idx = min(max(A, 1), LVL - 1);
        ea = make_float4(INF, INF, s_uv[idx - 1], s_uv[idx]);
        eb = make_float4(0.f, 0.f, 0.f, __int_as_float(idx - 1));
    } else if (cnt <= 2 && A >= 1 && A + cnt <= LVL - 1) {
        // no clipping anywhere in range: idx = A + sel, sel in [0, cnt]
        float p0 = s_uv[A];
        float p1 = (cnt >= 2) ? s_uv[A + 1] : INF;
        float c0 = s_uv[A - 1];
        float c1 = s_uv[A];
        float c2 = s_uv[A + 1];                            // A+1 <= 255
        float c3 = (A + 2 <= LVL - 1) ? s_uv[A + 2] : 0.f; // used only if cnt==2
        ea = make_float4(p0, p1, c0, c1);
        eb = make_float4(c2, c3, 0.f, __int_as_float(A - 1));
    } else {
        // rare: >=3 points or clipped edge region -> exact masked scan
        ea = make_float4(0.f, 0.f, 0.f, 0.f);
        eb = make_float4(0.f, 0.f, 0.f, __int_as_float(-(A + 1)));
    }
    lutA[b] = ea;
    lutB[b] = eb;
}

// ---------------- main kernel ----------------
__global__ __launch_bounds__(256) void agc_quant_lut(
    const float* __restrict__ inputs,
    const float* __restrict__ means,
    const float* __restrict__ uv,
    const float4* __restrict__ lutA,
    const float4* __restrict__ lutB,
    float* __restrict__ out_deq,
    float* __restrict__ out_sym,
    int n4, int n, int nfull)
{
    __shared__ float  s_uv[LVL];
    __shared__ float4 s_A[NB];
    __shared__ float4 s_B[NB];

    int t = threadIdx.x;
    s_uv[t] = uv[t];
    #pragma unroll
    for (int q = 0; q < NB / 256; ++q) {
        int j = q * 256 + t;
        s_A[j] = lutA[j];
        s_B[j] = lutB[j];
    }
    __syncthreads();

    const float lo    = s_uv[0];
    const float scale = (float)NB / (s_uv[LVL - 1] - lo);

    const int i0 = blockIdx.x * (256 * QPT) + t;
    const bool full = (blockIdx.x < nfull);

    // ---- load phase: all 2*QPT global loads in flight ----
    float4 in[QPT], mn[QPT];
    if (full) {
        #pragma unroll
        for (int k = 0; k < QPT; ++k) {
            int i = i0 + k * 256;
            in[k] = reinterpret_cast<const float4*>(inputs)[i];
            mn[k] = reinterpret_cast<const float4*>(means)[i];
        }
    } else {
        #pragma unroll
        for (int k = 0; k < QPT; ++k) {
            int i = i0 + k * 256;
            if (i < n4) {
                in[k] = reinterpret_cast<const float4*>(inputs)[i];
                mn[k] = reinterpret_cast<const float4*>(means)[i];
            }
        }
    }

    // ---- compute + store ----
    #pragma unroll
    for (int k = 0; k < QPT; ++k) {
        int i = i0 + k * 256;
        if (!full && i >= n4) continue;

        float vs[4] = {in[k].x - mn[k].x, in[k].y - mn[k].y,
                       in[k].z - mn[k].z, in[k].w - mn[k].w};
        float ms[4] = {mn[k].x, mn[k].y, mn[k].z, mn[k].w};
        float dq[4], sy[4];

        #pragma unroll
        for (int e = 0; e < 4; ++e) {
            float v = vs[e];
            int b = bucket_of(v, lo, scale);

            float4 A4 = s_A[b];          // {p0, p1, c0, c1}
            float4 B4 = s_B[b];          // {c2, c3, -, basepack}
            int bp = __float_as_int(B4.w);

            float left, right;
            int base;
            if (bp >= 0) {
                // branchless (compiler -> cndmask): sel in {0,1,2}
                int sel = (A4.x < v) + (A4.y < v);
                left  = (sel == 0) ? A4.z : ((sel == 1) ? A4.w : B4.x);
                right = (sel == 0) ? A4.w : ((sel == 1) ? B4.x : B4.y);
                base  = bp + sel;
            } else {
                // rare masked path: exact lower_bound scan, start is valid
                int s = -bp - 1;
                while (s < LVL && s_uv[s] < v) ++s;
                int idx = min(max(s, 1), LVL - 1);
                left  = s_uv[idx - 1];
                right = s_uv[idx];
                base  = idx - 1;
            }

            bool tl = (fabsf(v - left) <= fabsf(v - right));  // identical to reference
            sy[e] = (float)(base + (tl ? 0 : 1));
            dq[e] = (tl ? left : right) + ms[e];
        }

        reinterpret_cast<float4*>(out_deq)[i] = make_float4(dq[0], dq[1], dq[2], dq[3]);
        reinterpret_cast<float4*>(out_sym)[i] = make_float4(sy[0], sy[1], sy[2], sy[3]);
    }

    // tail (n % 4 != 0) — n here is 12.58M, rem = 0
    if (blockIdx.x == 0 && t == 0) {
        for (int j = n4 * 4; j < n; ++j) {
            float m = means[j];
            float v = inputs[j] - m;
            int l = 0, h = LVL;
            for (int s = 0; s < 8; ++s) {
                int mm = (l + h) >> 1;
                bool r = (s_uv[mm] < v);
                l = r ? (mm + 1) : l;
                h = r ? h : mm;
            }
            int idx = min(max(l, 1), LVL - 1);
            float left = s_uv[idx - 1], right = s_uv[idx];
            bool tl = fabsf(v - left) <= fabsf(v - right);
            out_deq[j] = (tl ? left : right) + m;
            out_sym[j] = (float)(tl ? idx - 1 : idx);
        }
    }
}

// ---------------- safety fallback (no/short workspace): binary-search kernel ----
__global__ __launch_bounds__(256) void agc_quant_fallback(
    const float* __restrict__ inputs,
    const float* __restrict__ means,
    const float* __restrict__ uv,
    float* __restrict__ out_deq,
    float* __restrict__ out_sym,
    int n4, int n)
{
    __shared__ float s_uv[LVL];
    s_uv[threadIdx.x] = uv[threadIdx.x];
    __syncthreads();

    int i = blockIdx.x * blockDim.x + threadIdx.x;
    if (i < n4) {
        float4 in = reinterpret_cast<const float4*>(inputs)[i];
        float4 mn = reinterpret_cast<const float4*>(means)[i];
        float vs[4] = {in.x - mn.x, in.y - mn.y, in.z - mn.z, in.w - mn.w};
        float ms[4] = {mn.x, mn.y, mn.z, mn.w};
        float dq[4], sy[4];
        #pragma unroll
        for (int k = 0; k < 4; ++k) {
            float v = vs[k];
            int lo = 0, hi = LVL;
            #pragma unroll
            for (int s = 0; s < 8; ++s) {
                int mid = (lo + hi) >> 1;
                bool r = (s_uv[mid] < v);
                lo = r ? (mid + 1) : lo;
                hi = r ? hi : mid;
            }
            int idx = min(max(lo, 1), LVL - 1);
            float left = s_uv[idx - 1], right = s_uv[idx];
            bool tl = (fabsf(v - left) <= fabsf(v - right));
            sy[k] = (float)(tl ? idx - 1 : idx);
            dq[k] = (tl ? left : right) + ms[k];
        }
        reinterpret_cast<float4*>(out_deq)[i] = make_float4(dq[0], dq[1], dq[2], dq[3]);
        reinterpret_cast<float4*>(out_sym)[i] = make_float4(sy[0], sy[1], sy[2], sy[3]);
    }
    if (blockIdx.x == 0 && threadIdx.x == 0) {
        for (int j = n4 * 4; j < n; ++j) {
            float m = means[j];
            float v = inputs[j] - m;
            int lo = 0, hi = LVL;
            for (int s = 0; s < 8; ++s) {
                int mid = (lo + hi) >> 1;
                bool r = (s_uv[mid] < v);
                lo = r ? (mid + 1) : lo;
                hi = r ? hi : mid;
            }
            int idx = min(max(lo, 1), LVL - 1);
            float left = s_uv[idx - 1], right = s_uv[idx];
            bool tl = fabsf(v - left) <= fabsf(v - right);
            out_deq[j] = (tl ? left : right) + m;
            out_sym[j] = (float)(tl ? idx - 1 : idx);
        }
    }
}

extern "C" void kernel_launch(void* const* d_in, const int* in_sizes, int n_in,
                              void* d_out, int out_size, void* d_ws, size_t ws_size,
                              hipStream_t stream)
{
    const float* inputs = (const float*)d_in[0];
    const float* means  = (const float*)d_in[1];
    const float* uv     = (const float*)d_in[2];

    int n  = in_sizes[0];        // 12,582,912
    int n4 = n / 4;

    float* out     = (float*)d_out;
    float* out_deq = out;        // first N: dequant
    float* out_sym = out + n;    // second N: symbols (exact float values)

    size_t need = (size_t)NB * 2 * sizeof(float4);   // 32 KB
    if (d_ws != nullptr && ws_size >= need) {
        float4* lutA = (float4*)d_ws;
        float4* lutB = lutA + NB;
        agc_build_lut<<<NB / 256, 256, 0, stream>>>(uv, lutA, lutB);

        int per_blk = 256 * QPT;                       // quads per block
        int nfull   = n4 / per_blk;                    // fully-covered blocks
        int blocks  = (n4 + per_blk - 1) / per_blk;    // 3072 for this shape
        if (blocks < 1) blocks = 1;
        agc_quant_lut<<<blocks, 256, 0, stream>>>(
            inputs, means, uv, lutA, lutB,
            out_deq, out_sym, n4, n, nfull);
    } else {
        int blocks = (n4 + 255) / 256;
        if (blocks < 1) blocks = 1;
        agc_quant_fallback<<<blocks, 256, 0, stream>>>(
            inputs, means, uv, out_deq, out_sym, n4, n);
    }
}